// Round 6
// baseline (180.984 us; speedup 1.0000x reference)
//
#include <hip/hip_runtime.h>

// MSAttention collapses: out = sum_n V (attention rows normalize to 1; m,n are
// independently summed einsum indices). Only V-halves (rows 256..511) of kv
// weights matter; value block-sums commute with the linear projection:
//   out0 = S1 @ Wkid0 + up4(S0 @ Wpeer0)
//   out1 = S2 @ Wkid1 + up2(S1 @ Wpeer1 + x0 @ Wpar1)
//   out2 =              up2(S2 @ Wpeer2 + x1 @ Wpar2)
// Sk = 2x2 (4x4 for S0) spatial block-sum of xk. Output f32.
// All GEMMs via v_mfma_f32_16x16x32_bf16; out1 coarse term computed in-block
// (32-row tiles need exactly 16 contiguous S1 coarse rows) -> no out1 RMW.

constexpr int FD = 256;

typedef __attribute__((ext_vector_type(8))) short short8;   // 8 bf16
typedef __attribute__((ext_vector_type(4))) float floatx4;  // C/D frag

__device__ inline unsigned short bf16bits(float f) {
  unsigned u = __builtin_bit_cast(unsigned, f);
  return (unsigned short)((u + 0x7fffu + ((u >> 16) & 1u)) >> 16);
}
__device__ inline ushort4 cvt4(float4 v) {
  ushort4 o;
  o.x = bf16bits(v.x); o.y = bf16bits(v.y);
  o.z = bf16bits(v.z); o.w = bf16bits(v.w);
  return o;
}

// ws layout (bf16 elements):
//   S0b [144,256] (128 valid + pad)   S1b [2048,256]   S2b [8192,256]
//   Wb 7x[256,256]: peer0,kid0,peer1,par1,kid1,peer2,par2
//   x0b [2048,256]   x1b [8192,256]
constexpr size_t OFF_S1 = 144 * 256;
constexpr size_t OFF_S2 = OFF_S1 + 2048 * 256;
constexpr size_t OFF_W = OFF_S2 + 8192 * 256;
constexpr size_t OFF_X0 = OFF_W + 7 * 65536;
constexpr size_t OFF_X1 = OFF_X0 + 2048 * 256;  // end: 5738496 el = 11.5 MB

// K1: blocksums (f32->bf16) + bf16 copies of x0,x1 + V-half weight cvt.
__global__ __launch_bounds__(256) void prep(
    const float4* __restrict__ x0, const float4* __restrict__ x1,
    const float4* __restrict__ x2, const float* __restrict__ wp0,
    const float* __restrict__ wk0, const float* __restrict__ wp1,
    const float* __restrict__ wq1, const float* __restrict__ wk1,
    const float* __restrict__ wp2, const float* __restrict__ wq2,
    unsigned short* __restrict__ ws) {
  int blk = blockIdx.x;
  int t = threadIdx.x;
  if (blk < 2592) {  // block sums: 4 rows x 64 float4-channels
    const float4* x;
    unsigned short* S;
    unsigned short* xo = nullptr;
    int Hs, Ws, hb, row0;
    if (blk < 32) {
      x = x0; S = ws; xo = ws + OFF_X0; Hs = 4; Ws = 4; hb = 4; row0 = blk * 4;
    } else if (blk < 544) {
      x = x1; S = ws + OFF_S1; xo = ws + OFF_X1;
      Hs = 16; Ws = 16; hb = 2; row0 = (blk - 32) * 4;
    } else {
      x = x2; S = ws + OFF_S2; Hs = 32; Ws = 32; hb = 2; row0 = (blk - 544) * 4;
    }
    int c = t & 63;
    int row = row0 + (t >> 6);
    int bw = row % Ws;
    int t2 = row / Ws;
    int bh = t2 % Hs;
    int b = t2 / Hs;
    int W = Ws * hb;
    size_t base4 = (((size_t)b * Hs * hb + bh * hb) * W + bw * hb) * 64 + c;
    const float4* xb = x + base4;
    float4 s = {0.f, 0.f, 0.f, 0.f};
    for (int i = 0; i < hb; ++i)
      for (int j = 0; j < hb; ++j) {
        float4 v = xb[(size_t)(i * W + j) * 64];
        s.x += v.x; s.y += v.y; s.z += v.z; s.w += v.w;
        if (xo) *(ushort4*)(xo + (base4 + (size_t)(i * W + j) * 64) * 4) = cvt4(v);
      }
    *(ushort4*)(S + (size_t)row * FD + c * 4) = cvt4(s);
  } else {  // weight cvt: 7 mats x 64 groups of 4 rows (V half = rows 256..511)
    int wb = blk - 2592;
    int mat = wb >> 6;
    int row = (wb & 63) * 4 + (t >> 6);
    int c4 = (t & 63) * 4;
    const float* src;
    switch (mat) {
      case 0: src = wp0; break;
      case 1: src = wk0; break;
      case 2: src = wp1; break;
      case 3: src = wq1; break;
      case 4: src = wk1; break;
      case 5: src = wp2; break;
      default: src = wq2; break;
    }
    float4 v = *(const float4*)(src + (size_t)(256 + row) * FD + c4);
    *(ushort4*)(ws + OFF_W + (size_t)mat * 65536 + (size_t)row * FD + c4) =
        cvt4(v);
  }
}

#define MFMA(a, b, c) __builtin_amdgcn_mfma_f32_16x16x32_bf16(a, b, c, 0, 0, 0)

// K2: blocks [0,1024): 32 S2-rows x 64 cols:
//       out1 = S2@Wk1 + up2(S1@Wp1 + x0b@Wq1);  out2 = up2(S2@Wp2 + x1b@Wq2)
//     blocks [1024,1152): out0 = S1@Wk0 + up4(S0@Wp0)  (64 rows x 64 cols)
__global__ __launch_bounds__(256) void gemm(const unsigned short* __restrict__ ws,
                                            float* __restrict__ out0,
                                            float* __restrict__ out1,
                                            float* __restrict__ out2) {
  __shared__ float lds[4][16][17];  // per-wave 16x16 coarse tile, padded
  int t = threadIdx.x;
  int l = t & 63;
  int wv = t >> 6;
  int c = l & 15, q = l >> 4;
  const short8* Wb = (const short8*)(ws + OFF_W);

  if (blockIdx.x < 1024) {
    int r0 = (blockIdx.x >> 2) * 32;   // S2-row tile (== out1 row tile)
    int n0 = (blockIdx.x & 3) * 64;
    int n = n0 + wv * 16 + c;
    const short8* S2b = (const short8*)(ws + OFF_S2);
    const short8* X1b = (const short8*)(ws + OFF_X1);
    // coarse S1/x0 rows: b*256 + (h/2)*16, 16 contiguous rows
    int cb0 = (r0 >> 10) * 256 + (((r0 >> 5) & 31) >> 1) * 16;
    const short8* aS1 = (const short8*)(ws + OFF_S1) + (size_t)(cb0 + c) * 32 + q;
    const short8* aX0 = (const short8*)(ws + OFF_X0) + (size_t)(cb0 + c) * 32 + q;
    const short8 *aS2[2], *aX1[2];
#pragma unroll
    for (int mt = 0; mt < 2; ++mt) {
      aS2[mt] = S2b + (size_t)(r0 + mt * 16 + c) * 32 + q;
      aX1[mt] = X1b + (size_t)(r0 + mt * 16 + c) * 32 + q;
    }
    const short8* bK1 = Wb + (size_t)4 * 8192 + (size_t)n * 32 + q;
    const short8* bP2 = Wb + (size_t)5 * 8192 + (size_t)n * 32 + q;
    const short8* bQ2 = Wb + (size_t)6 * 8192 + (size_t)n * 32 + q;
    const short8* bP1 = Wb + (size_t)2 * 8192 + (size_t)n * 32 + q;
    const short8* bQ1 = Wb + (size_t)3 * 8192 + (size_t)n * 32 + q;
    floatx4 accK[2] = {0, 0};
    floatx4 accC2[2] = {0, 0};
    floatx4 accC1 = {0, 0, 0, 0};
#pragma unroll 4
    for (int kk = 0; kk < 8; ++kk) {
      short8 k1 = bK1[kk * 4], p2 = bP2[kk * 4], q2 = bQ2[kk * 4];
      short8 p1 = bP1[kk * 4], q1 = bQ1[kk * 4];
      accC1 = MFMA(aS1[kk * 4], p1, accC1);
      accC1 = MFMA(aX0[kk * 4], q1, accC1);
#pragma unroll
      for (int mt = 0; mt < 2; ++mt) {
        short8 a = aS2[mt][kk * 4];
        accK[mt] = MFMA(a, k1, accK[mt]);
        accC2[mt] = MFMA(a, p2, accC2[mt]);
        accC2[mt] = MFMA(aX1[mt][kk * 4], q2, accC2[mt]);
      }
    }
    // coarse tile -> LDS (row = w1, col = c), then up2 gather
#pragma unroll
    for (int r = 0; r < 4; ++r) lds[wv][4 * q + r][c] = accC1[r];
    __syncthreads();
#pragma unroll
    for (int mt = 0; mt < 2; ++mt)
#pragma unroll
      for (int r = 0; r < 4; ++r) {
        int rg = r0 + mt * 16 + 4 * q + r;
        int w = rg & 31;
        out1[(size_t)rg * FD + n] = accK[mt][r] + lds[wv][w >> 1][c];
        int b = rg >> 10, h = (rg >> 5) & 31;
        size_t o = ((size_t)b * 4096 + h * 128 + 2 * w) * FD + n;
        float v = accC2[mt][r];
        out2[o] = v;
        out2[o + FD] = v;
        out2[o + 16384] = v;
        out2[o + 16384 + FD] = v;
      }
  } else {
    int bid = blockIdx.x - 1024;
    int r0 = (bid >> 2) * 64;  // S1-row tile (== out0 row tile)
    int n0 = (bid & 3) * 64;
    int n = n0 + wv * 16 + c;
    const short8* S1b = (const short8*)(ws + OFF_S1);
    const short8* aC = (const short8*)ws + (size_t)((r0 >> 4) + c) * 32 + q;
    const short8* bK = Wb + (size_t)1 * 8192 + (size_t)n * 32 + q;  // kid0
    const short8* bP = Wb + (size_t)0 * 8192 + (size_t)n * 32 + q;  // peer0
    const short8* aS[4];
#pragma unroll
    for (int mt = 0; mt < 4; ++mt)
      aS[mt] = S1b + (size_t)(r0 + mt * 16 + c) * 32 + q;
    floatx4 accK[4] = {0, 0, 0, 0};
    floatx4 accC = {0, 0, 0, 0};
#pragma unroll 4
    for (int kk = 0; kk < 8; ++kk) {
      short8 b0 = bK[kk * 4], b1 = bP[kk * 4];
      accC = MFMA(aC[kk * 4], b1, accC);
#pragma unroll
      for (int mt = 0; mt < 4; ++mt) accK[mt] = MFMA(aS[mt][kk * 4], b0, accK[mt]);
    }
    // up4: out row needs S0 row (r0>>4)+q -> C-tile row q, col c
    float s0 = __shfl(accC[0], c), s1 = __shfl(accC[1], c);
    float s2 = __shfl(accC[2], c), s3 = __shfl(accC[3], c);
    float cv = q == 0 ? s0 : q == 1 ? s1 : q == 2 ? s2 : s3;
#pragma unroll
    for (int mt = 0; mt < 4; ++mt)
#pragma unroll
      for (int r = 0; r < 4; ++r)
        out0[(size_t)(r0 + mt * 16 + 4 * q + r) * FD + n] = accK[mt][r] + cv;
  }
}

extern "C" void kernel_launch(void* const* d_in, const int* in_sizes, int n_in,
                              void* d_out, int out_size, void* d_ws,
                              size_t ws_size, hipStream_t stream) {
  const float* x0 = (const float*)d_in[0];  // [8,16,16,256]
  const float* x1 = (const float*)d_in[1];  // [8,32,32,256]
  const float* x2 = (const float*)d_in[2];  // [8,64,64,256]

  const float *kvpeer0, *kvpeer1, *kvpeer2, *kvpar1, *kvpar2, *kvkid0, *kvkid1;
  if (n_in > 4 && in_sizes[4] == 2 * FD * FD) {  // setup_inputs dict order
    kvpeer0 = (const float*)d_in[4];
    kvpeer1 = (const float*)d_in[6];
    kvpeer2 = (const float*)d_in[8];
    kvpar1 = (const float*)d_in[10];
    kvpar2 = (const float*)d_in[12];
    kvkid0 = (const float*)d_in[14];
    kvkid1 = (const float*)d_in[16];
  } else {  // reference() signature order
    kvpeer0 = (const float*)d_in[6];
    kvpeer1 = (const float*)d_in[7];
    kvpeer2 = (const float*)d_in[8];
    kvpar1 = (const float*)d_in[11];
    kvpar2 = (const float*)d_in[12];
    kvkid0 = (const float*)d_in[15];
    kvkid1 = (const float*)d_in[16];
  }

  unsigned short* ws = (unsigned short*)d_ws;  // ~11.5 MB bf16 scratch
  float* out0 = (float*)d_out;
  float* out1 = out0 + (size_t)8 * 16 * 16 * FD;
  float* out2 = out1 + (size_t)8 * 32 * 32 * FD;

  prep<<<3040, 256, 0, stream>>>((const float4*)x0, (const float4*)x1,
                                 (const float4*)x2, kvpeer0, kvkid0, kvpeer1,
                                 kvpar1, kvkid1, kvpeer2, kvpar2, ws);
  gemm<<<1152, 256, 0, stream>>>(ws, out0, out1, out2);
}

// Round 7
// 169.751 us; speedup vs baseline: 1.0662x; 1.0662x over previous
//
#include <hip/hip_runtime.h>

// MSAttention collapses: out = sum_n V (attention rows normalize to 1; m,n are
// independently summed einsum indices). Only V-halves (rows 256..511) of kv
// weights matter; value block-sums commute with the linear projection:
//   out0 = S1 @ Wkid0 + up4(S0 @ Wpeer0)
//   out1 = S2 @ Wkid1 + up2(S1 @ Wpeer1 + x0 @ Wpar1)
//   out2 =              up2(S2 @ Wpeer2 + x1 @ Wpar2)
// Sk = 2x2 (4x4 for S0) spatial block-sum of xk. Output f32.
// GEMMs via v_mfma_f32_16x16x32_bf16. Weight panels are preloaded into
// register arrays and A-frags are batch-loaded (16 independent dwordx4 in
// flight) -- round-6 counters showed the interleaved-stream loop serialized
// at L2 latency (MfmaUtil 3%, 28K cyc/wave).

constexpr int FD = 256;

typedef __attribute__((ext_vector_type(8))) short short8;   // 8 bf16
typedef __attribute__((ext_vector_type(4))) float floatx4;  // C/D frag

__device__ inline unsigned short bf16bits(float f) {
  unsigned u = __builtin_bit_cast(unsigned, f);
  return (unsigned short)((u + 0x7fffu + ((u >> 16) & 1u)) >> 16);
}
__device__ inline ushort4 cvt4(float4 v) {
  ushort4 o;
  o.x = bf16bits(v.x); o.y = bf16bits(v.y);
  o.z = bf16bits(v.z); o.w = bf16bits(v.w);
  return o;
}

// ws layout (bf16 elements):
//   S0b [144,256] (128 valid + pad)   S1b [2048,256]   S2b [8192,256]
//   Wb 7x[256,256]: peer0,kid0,peer1,par1,kid1,peer2,par2
//   x0b [2048,256]   x1b [8192,256]
constexpr size_t OFF_S1 = 144 * 256;
constexpr size_t OFF_S2 = OFF_S1 + 2048 * 256;
constexpr size_t OFF_W = OFF_S2 + 8192 * 256;
constexpr size_t OFF_X0 = OFF_W + 7 * 65536;
constexpr size_t OFF_X1 = OFF_X0 + 2048 * 256;  // end: 5738496 el = 11.5 MB

// K1: blocksums (f32->bf16) + bf16 copies of x0,x1 + V-half weight cvt.
__global__ __launch_bounds__(256) void prep(
    const float4* __restrict__ x0, const float4* __restrict__ x1,
    const float4* __restrict__ x2, const float* __restrict__ wp0,
    const float* __restrict__ wk0, const float* __restrict__ wp1,
    const float* __restrict__ wq1, const float* __restrict__ wk1,
    const float* __restrict__ wp2, const float* __restrict__ wq2,
    unsigned short* __restrict__ ws) {
  int blk = blockIdx.x;
  int t = threadIdx.x;
  if (blk < 2592) {  // block sums: 4 rows x 64 float4-channels
    const float4* x;
    unsigned short* S;
    unsigned short* xo = nullptr;
    int Hs, Ws, hb, row0;
    if (blk < 32) {
      x = x0; S = ws; xo = ws + OFF_X0; Hs = 4; Ws = 4; hb = 4; row0 = blk * 4;
    } else if (blk < 544) {
      x = x1; S = ws + OFF_S1; xo = ws + OFF_X1;
      Hs = 16; Ws = 16; hb = 2; row0 = (blk - 32) * 4;
    } else {
      x = x2; S = ws + OFF_S2; Hs = 32; Ws = 32; hb = 2; row0 = (blk - 544) * 4;
    }
    int c = t & 63;
    int row = row0 + (t >> 6);
    int bw = row % Ws;
    int t2 = row / Ws;
    int bh = t2 % Hs;
    int b = t2 / Hs;
    int W = Ws * hb;
    size_t base4 = (((size_t)b * Hs * hb + bh * hb) * W + bw * hb) * 64 + c;
    const float4* xb = x + base4;
    float4 s = {0.f, 0.f, 0.f, 0.f};
    for (int i = 0; i < hb; ++i)
      for (int j = 0; j < hb; ++j) {
        float4 v = xb[(size_t)(i * W + j) * 64];
        s.x += v.x; s.y += v.y; s.z += v.z; s.w += v.w;
        if (xo) *(ushort4*)(xo + (base4 + (size_t)(i * W + j) * 64) * 4) = cvt4(v);
      }
    *(ushort4*)(S + (size_t)row * FD + c * 4) = cvt4(s);
  } else {  // weight cvt: 7 mats x 64 groups of 4 rows (V half = rows 256..511)
    int wb = blk - 2592;
    int mat = wb >> 6;
    int row = (wb & 63) * 4 + (t >> 6);
    int c4 = (t & 63) * 4;
    const float* src;
    switch (mat) {
      case 0: src = wp0; break;
      case 1: src = wk0; break;
      case 2: src = wp1; break;
      case 3: src = wq1; break;
      case 4: src = wk1; break;
      case 5: src = wp2; break;
      default: src = wq2; break;
    }
    float4 v = *(const float4*)(src + (size_t)(256 + row) * FD + c4);
    *(ushort4*)(ws + OFF_W + (size_t)mat * 65536 + (size_t)row * FD + c4) =
        cvt4(v);
  }
}

#define MFMA(a, b, c) __builtin_amdgcn_mfma_f32_16x16x32_bf16(a, b, c, 0, 0, 0)

// K2: blocks [0,512):     out2 = up2(S2@Wp2 + x1b@Wq2)        64 rows x 64 cols
//     blocks [512,1024):  out1 = S2@Wk1 + up2(S1@Wp1+x0b@Wq1) 64 rows x 64 cols
//     blocks [1024,1152): out0 = S1@Wk0 + up4(S0@Wp0)         64 rows x 64 cols
__global__ __launch_bounds__(256, 2) void gemm(
    const unsigned short* __restrict__ ws, float* __restrict__ out0,
    float* __restrict__ out1, float* __restrict__ out2) {
  __shared__ float lds[4][16][17];  // per-wave private 16x16 coarse tile
  int t = threadIdx.x;
  int l = t & 63;
  int wv = t >> 6;
  int c = l & 15, q = l >> 4;
  const short8* Wb = (const short8*)(ws + OFF_W);

  if (blockIdx.x < 512) {
    int r0 = (blockIdx.x >> 2) * 64;
    int n0 = (blockIdx.x & 3) * 64;
    int n = n0 + wv * 16 + c;
    const short8* bP = Wb + (size_t)5 * 8192 + (size_t)n * 32 + q;  // peer2
    const short8* bQ = Wb + (size_t)6 * 8192 + (size_t)n * 32 + q;  // par2
    short8 Bp[8], Bq[8];
#pragma unroll
    for (int kk = 0; kk < 8; ++kk) {
      Bp[kk] = bP[kk * 4];
      Bq[kk] = bQ[kk * 4];
    }
    const short8* S2b = (const short8*)(ws + OFF_S2);
    const short8* X1b = (const short8*)(ws + OFF_X1);
#pragma unroll
    for (int mt = 0; mt < 4; ++mt) {
      const short8* aS = S2b + (size_t)(r0 + mt * 16 + c) * 32 + q;
      const short8* aX = X1b + (size_t)(r0 + mt * 16 + c) * 32 + q;
      short8 As[8], Ax[8];
#pragma unroll
      for (int kk = 0; kk < 8; ++kk) {
        As[kk] = aS[kk * 4];
        Ax[kk] = aX[kk * 4];
      }
      floatx4 acc = {0, 0, 0, 0};
#pragma unroll
      for (int kk = 0; kk < 8; ++kk) {
        acc = MFMA(As[kk], Bp[kk], acc);
        acc = MFMA(Ax[kk], Bq[kk], acc);
      }
#pragma unroll
      for (int r = 0; r < 4; ++r) {
        int rg = r0 + mt * 16 + 4 * q + r;
        int b = rg >> 10, h = (rg >> 5) & 31, w = rg & 31;
        size_t o = ((size_t)b * 4096 + h * 128 + 2 * w) * FD + n;
        float v = acc[r];
        out2[o] = v;
        out2[o + FD] = v;
        out2[o + 16384] = v;
        out2[o + 16384 + FD] = v;
      }
    }
  } else if (blockIdx.x < 1024) {
    int bid = blockIdx.x - 512;
    int r0 = (bid >> 2) * 64;
    int n0 = (bid & 3) * 64;
    int n = n0 + wv * 16 + c;
    const short8* bK = Wb + (size_t)4 * 8192 + (size_t)n * 32 + q;  // kid1
    const short8* bP = Wb + (size_t)2 * 8192 + (size_t)n * 32 + q;  // peer1
    const short8* bQ = Wb + (size_t)3 * 8192 + (size_t)n * 32 + q;  // par1
    short8 Bk[8], Bp[8], Bq[8];
#pragma unroll
    for (int kk = 0; kk < 8; ++kk) {
      Bk[kk] = bK[kk * 4];
      Bp[kk] = bP[kk * 4];
      Bq[kk] = bQ[kk * 4];
    }
    // coarse S1/x0 rows: b*256 + (h0/2)*16, 16 contiguous rows
    int cb0 = (r0 >> 10) * 256 + (((r0 >> 5) & 31) >> 1) * 16;
    {
      const short8* aS1 =
          (const short8*)(ws + OFF_S1) + (size_t)(cb0 + c) * 32 + q;
      const short8* aX0 =
          (const short8*)(ws + OFF_X0) + (size_t)(cb0 + c) * 32 + q;
      short8 A1[8], A0[8];
#pragma unroll
      for (int kk = 0; kk < 8; ++kk) {
        A1[kk] = aS1[kk * 4];
        A0[kk] = aX0[kk * 4];
      }
      floatx4 accC = {0, 0, 0, 0};
#pragma unroll
      for (int kk = 0; kk < 8; ++kk) {
        accC = MFMA(A1[kk], Bp[kk], accC);
        accC = MFMA(A0[kk], Bq[kk], accC);
      }
      // coarse tile -> per-wave LDS (row = w1, col = c); same-wave RAW only
#pragma unroll
      for (int r = 0; r < 4; ++r) lds[wv][4 * q + r][c] = accC[r];
    }
    const short8* S2b = (const short8*)(ws + OFF_S2);
#pragma unroll
    for (int mt = 0; mt < 4; ++mt) {
      const short8* aS = S2b + (size_t)(r0 + mt * 16 + c) * 32 + q;
      short8 As[8];
#pragma unroll
      for (int kk = 0; kk < 8; ++kk) As[kk] = aS[kk * 4];
      floatx4 acc = {0, 0, 0, 0};
#pragma unroll
      for (int kk = 0; kk < 8; ++kk) acc = MFMA(As[kk], Bk[kk], acc);
#pragma unroll
      for (int r = 0; r < 4; ++r) {
        int rg = r0 + mt * 16 + 4 * q + r;
        int w = rg & 31;
        out1[(size_t)rg * FD + n] = acc[r] + lds[wv][w >> 1][c];
      }
    }
  } else {
    int bid = blockIdx.x - 1024;
    int r0 = (bid >> 2) * 64;  // out0/S1 row tile
    int n0 = (bid & 3) * 64;
    int n = n0 + wv * 16 + c;
    const short8* bK = Wb + (size_t)1 * 8192 + (size_t)n * 32 + q;  // kid0
    const short8* bP = Wb + (size_t)0 * 8192 + (size_t)n * 32 + q;  // peer0
    short8 Bk[8], Bp[8];
#pragma unroll
    for (int kk = 0; kk < 8; ++kk) {
      Bk[kk] = bK[kk * 4];
      Bp[kk] = bP[kk * 4];
    }
    floatx4 accC = {0, 0, 0, 0};
    {
      const short8* aC = (const short8*)ws + (size_t)((r0 >> 4) + c) * 32 + q;
      short8 AC[8];
#pragma unroll
      for (int kk = 0; kk < 8; ++kk) AC[kk] = aC[kk * 4];
#pragma unroll
      for (int kk = 0; kk < 8; ++kk) accC = MFMA(AC[kk], Bp[kk], accC);
    }
    // up4: out row (h0+mt, w=4q+r) needs S0 row (r0>>4)+q -> C row q, col c
    float s0 = __shfl(accC[0], c), s1 = __shfl(accC[1], c);
    float s2 = __shfl(accC[2], c), s3 = __shfl(accC[3], c);
    float cv = q == 0 ? s0 : q == 1 ? s1 : q == 2 ? s2 : s3;
    const short8* S1b = (const short8*)(ws + OFF_S1);
#pragma unroll
    for (int mt = 0; mt < 4; ++mt) {
      const short8* aS = S1b + (size_t)(r0 + mt * 16 + c) * 32 + q;
      short8 As[8];
#pragma unroll
      for (int kk = 0; kk < 8; ++kk) As[kk] = aS[kk * 4];
      floatx4 acc = {0, 0, 0, 0};
#pragma unroll
      for (int kk = 0; kk < 8; ++kk) acc = MFMA(As[kk], Bk[kk], acc);
#pragma unroll
      for (int r = 0; r < 4; ++r)
        out0[(size_t)(r0 + mt * 16 + 4 * q + r) * FD + n] = acc[r] + cv;
    }
  }
}

extern "C" void kernel_launch(void* const* d_in, const int* in_sizes, int n_in,
                              void* d_out, int out_size, void* d_ws,
                              size_t ws_size, hipStream_t stream) {
  const float* x0 = (const float*)d_in[0];  // [8,16,16,256]
  const float* x1 = (const float*)d_in[1];  // [8,32,32,256]
  const float* x2 = (const float*)d_in[2];  // [8,64,64,256]

  const float *kvpeer0, *kvpeer1, *kvpeer2, *kvpar1, *kvpar2, *kvkid0, *kvkid1;
  if (n_in > 4 && in_sizes[4] == 2 * FD * FD) {  // setup_inputs dict order
    kvpeer0 = (const float*)d_in[4];
    kvpeer1 = (const float*)d_in[6];
    kvpeer2 = (const float*)d_in[8];
    kvpar1 = (const float*)d_in[10];
    kvpar2 = (const float*)d_in[12];
    kvkid0 = (const float*)d_in[14];
    kvkid1 = (const float*)d_in[16];
  } else {  // reference() signature order
    kvpeer0 = (const float*)d_in[6];
    kvpeer1 = (const float*)d_in[7];
    kvpeer2 = (const float*)d_in[8];
    kvpar1 = (const float*)d_in[11];
    kvpar2 = (const float*)d_in[12];
    kvkid0 = (const float*)d_in[15];
    kvkid1 = (const float*)d_in[16];
  }

  unsigned short* ws = (unsigned short*)d_ws;  // ~11.5 MB bf16 scratch
  float* out0 = (float*)d_out;
  float* out1 = out0 + (size_t)8 * 16 * 16 * FD;
  float* out2 = out1 + (size_t)8 * 32 * 32 * FD;

  prep<<<3040, 256, 0, stream>>>((const float4*)x0, (const float4*)x1,
                                 (const float4*)x2, kvpeer0, kvkid0, kvpeer1,
                                 kvpar1, kvkid1, kvpeer2, kvpar2, ws);
  gemm<<<1152, 256, 0, stream>>>(ws, out0, out1, out2);
}

// Round 8
// 162.937 us; speedup vs baseline: 1.1108x; 1.0418x over previous
//
#include <hip/hip_runtime.h>

// MSAttention collapses: out = sum_n V (attention rows normalize to 1; m,n are
// independently summed einsum indices). Only V-halves (rows 256..511) of kv
// weights matter; value block-sums commute with the linear projection:
//   out0 = S1 @ Wkid0 + up4(S0 @ Wpeer0)
//   out1 = S2 @ Wkid1 + up2(S1 @ Wpeer1 + x0 @ Wpar1)
//   out2 =              up2(S2 @ Wpeer2 + x1 @ Wpar2)
// Sk = 2x2 (4x4 for S0) spatial block-sum of xk. Output f32.
// Round-7 lesson: register-batched loads get serialized by the VGPR-miser
// compiler (~800 cyc/load, MfmaUtil 3%). This version stages tiles through
// LDS: batch 9-12 global loads/thread -> sched_barrier -> ds_write ->
// barrier -> ds_read_b128 + v_mfma_f32_16x16x32_bf16.

constexpr int FD = 256;

typedef __attribute__((ext_vector_type(8))) short short8;   // 8 bf16
typedef __attribute__((ext_vector_type(4))) float floatx4;  // C/D frag

__device__ inline unsigned short bf16bits(float f) {
  unsigned u = __builtin_bit_cast(unsigned, f);
  return (unsigned short)((u + 0x7fffu + ((u >> 16) & 1u)) >> 16);
}
__device__ inline ushort4 cvt4(float4 v) {
  ushort4 o;
  o.x = bf16bits(v.x); o.y = bf16bits(v.y);
  o.z = bf16bits(v.z); o.w = bf16bits(v.w);
  return o;
}

// ws layout (bf16 elements):
//   S0b [144,256] (128 valid + pad)   S1b [2048,256]   S2b [8192,256]
//   Wb 7x[256,256]: peer0,kid0,peer1,par1,kid1,peer2,par2
//   x0b [2048,256]   x1b [8192,256]
constexpr size_t OFF_S1 = 144 * 256;
constexpr size_t OFF_S2 = OFF_S1 + 2048 * 256;
constexpr size_t OFF_W = OFF_S2 + 8192 * 256;
constexpr size_t OFF_X0 = OFF_W + 7 * 65536;
constexpr size_t OFF_X1 = OFF_X0 + 2048 * 256;  // end: 5738496 el = 11.5 MB

// K1: blocksums (f32->bf16) + bf16 copies of x0,x1 + V-half weight cvt.
__global__ __launch_bounds__(256) void prep(
    const float4* __restrict__ x0, const float4* __restrict__ x1,
    const float4* __restrict__ x2, const float* __restrict__ wp0,
    const float* __restrict__ wk0, const float* __restrict__ wp1,
    const float* __restrict__ wq1, const float* __restrict__ wk1,
    const float* __restrict__ wp2, const float* __restrict__ wq2,
    unsigned short* __restrict__ ws) {
  int blk = blockIdx.x;
  int t = threadIdx.x;
  if (blk < 2592) {  // block sums: 4 rows x 64 float4-channels
    const float4* x;
    unsigned short* S;
    unsigned short* xo = nullptr;
    int Hs, Ws, hb, row0;
    if (blk < 32) {
      x = x0; S = ws; xo = ws + OFF_X0; Hs = 4; Ws = 4; hb = 4; row0 = blk * 4;
    } else if (blk < 544) {
      x = x1; S = ws + OFF_S1; xo = ws + OFF_X1;
      Hs = 16; Ws = 16; hb = 2; row0 = (blk - 32) * 4;
    } else {
      x = x2; S = ws + OFF_S2; Hs = 32; Ws = 32; hb = 2; row0 = (blk - 544) * 4;
    }
    int c = t & 63;
    int row = row0 + (t >> 6);
    int bw = row % Ws;
    int t2 = row / Ws;
    int bh = t2 % Hs;
    int b = t2 / Hs;
    int W = Ws * hb;
    size_t base4 = (((size_t)b * Hs * hb + bh * hb) * W + bw * hb) * 64 + c;
    const float4* xb = x + base4;
    float4 s = {0.f, 0.f, 0.f, 0.f};
    for (int i = 0; i < hb; ++i)
      for (int j = 0; j < hb; ++j) {
        float4 v = xb[(size_t)(i * W + j) * 64];
        s.x += v.x; s.y += v.y; s.z += v.z; s.w += v.w;
        if (xo) *(ushort4*)(xo + (base4 + (size_t)(i * W + j) * 64) * 4) = cvt4(v);
      }
    *(ushort4*)(S + (size_t)row * FD + c * 4) = cvt4(s);
  } else {  // weight cvt: 7 mats x 64 groups of 4 rows (V half = rows 256..511)
    int wb = blk - 2592;
    int mat = wb >> 6;
    int row = (wb & 63) * 4 + (t >> 6);
    int c4 = (t & 63) * 4;
    const float* src;
    switch (mat) {
      case 0: src = wp0; break;
      case 1: src = wk0; break;
      case 2: src = wp1; break;
      case 3: src = wq1; break;
      case 4: src = wk1; break;
      case 5: src = wp2; break;
      default: src = wq2; break;
    }
    float4 v = *(const float4*)(src + (size_t)(256 + row) * FD + c4);
    *(ushort4*)(ws + OFF_W + (size_t)mat * 65536 + (size_t)row * FD + c4) =
        cvt4(v);
  }
}

#define MFMA(a, b, c) __builtin_amdgcn_mfma_f32_16x16x32_bf16(a, b, c, 0, 0, 0)

// LDS-staged GEMM. Block = 64 rows x 32 cols, K split in 2 halves of 128.
// Staging chunk ch = j*256 + t (16B each); LDS addr = ch*16 (region
// boundaries align with j boundaries). Streams in LDS as [kq][row] planes
// (2-way bank aliasing on ds_read_b128 = free).
//   blocks [0,1024):     out2 = up2(S2@Wp2 + x1b@Wq2)
//   blocks [1024,2048):  out1 = S2@Wk1 + up2(S1c@Wp1 + x0c@Wq1)
//   blocks [2048,2304):  out0 = S1@Wk0 + up4(S0c@Wp0)
__global__ __launch_bounds__(256) void gemm(const unsigned short* __restrict__ ws,
                                            float* __restrict__ out0,
                                            float* __restrict__ out1,
                                            float* __restrict__ out2) {
  __shared__ __align__(16) char smem[49152];
  int t = threadIdx.x;
  int l = t & 63;
  int wv = t >> 6;
  int c = l & 15, q = l >> 4;
  const unsigned short* Wb = ws + OFF_W;

  if (blockIdx.x < 1024) {  // ---- out2 ----
    int r0 = (int)(blockIdx.x >> 3) * 64;
    int n0 = (int)(blockIdx.x & 7) * 32;
    const unsigned short* gA0 = ws + OFF_S2;
    const unsigned short* gA1 = ws + OFF_X1;
    const unsigned short* gB0 = Wb + (size_t)5 * 65536;  // peer2
    const unsigned short* gB1 = Wb + (size_t)6 * 65536;  // par2
    floatx4 acc[2] = {{0, 0, 0, 0}, {0, 0, 0, 0}};
#pragma unroll
    for (int kh = 0; kh < 2; ++kh) {
      short8 v[12];
#pragma unroll
      for (int j = 0; j < 12; ++j) {
        int ch = j * 256 + t;
        const unsigned short* src;
        if (j < 4) {
          src = gA0 + (size_t)(r0 + (ch & 63)) * 256 + kh * 128 + (ch >> 6) * 8;
        } else if (j < 8) {
          int ca = ch - 1024;
          src = gA1 + (size_t)(r0 + (ca & 63)) * 256 + kh * 128 + (ca >> 6) * 8;
        } else if (j < 10) {
          int cb = ch - 2048;
          src = gB0 + (size_t)(n0 + (cb & 31)) * 256 + kh * 128 + (cb >> 5) * 8;
        } else {
          int cb = ch - 2560;
          src = gB1 + (size_t)(n0 + (cb & 31)) * 256 + kh * 128 + (cb >> 5) * 8;
        }
        v[j] = *(const short8*)src;
      }
      __builtin_amdgcn_sched_barrier(0);
#pragma unroll
      for (int j = 0; j < 12; ++j)
        *(short8*)(smem + (size_t)(j * 256 + t) * 16) = v[j];
      __syncthreads();
#pragma unroll
      for (int kk = 0; kk < 4; ++kk) {
        int kq = kk * 4 + q;
        short8 a0 = *(const short8*)(smem + (size_t)(kq * 64 + wv * 16 + c) * 16);
        short8 a1 =
            *(const short8*)(smem + 16384 + (size_t)(kq * 64 + wv * 16 + c) * 16);
#pragma unroll
        for (int nt = 0; nt < 2; ++nt) {
          short8 b0 =
              *(const short8*)(smem + 32768 + (size_t)(kq * 32 + nt * 16 + c) * 16);
          short8 b1 =
              *(const short8*)(smem + 40960 + (size_t)(kq * 32 + nt * 16 + c) * 16);
          acc[nt] = MFMA(a0, b0, acc[nt]);
          acc[nt] = MFMA(a1, b1, acc[nt]);
        }
      }
      __syncthreads();
    }
#pragma unroll
    for (int nt = 0; nt < 2; ++nt) {
      int n = n0 + nt * 16 + c;
#pragma unroll
      for (int r = 0; r < 4; ++r) {
        int rg = r0 + wv * 16 + 4 * q + r;
        int b = rg >> 10, h = (rg >> 5) & 31, w = rg & 31;
        size_t o = ((size_t)b * 4096 + h * 128 + 2 * w) * FD + n;
        float vv = acc[nt][r];
        out2[o] = vv;
        out2[o + FD] = vv;
        out2[o + 16384] = vv;
        out2[o + 16384 + FD] = vv;
      }
    }
  } else if (blockIdx.x < 2048) {  // ---- out1 ----
    int bid = blockIdx.x - 1024;
    int r0 = (bid >> 3) * 64;
    int n0 = (bid & 7) * 32;
    int cb0 = (r0 >> 10) * 256 + (((r0 >> 5) & 31) >> 1) * 16;
    const unsigned short* gS2 = ws + OFF_S2;
    const unsigned short* gS1 = ws + OFF_S1;
    const unsigned short* gX0 = ws + OFF_X0;
    const unsigned short* gBk = Wb + (size_t)4 * 65536;  // kid1
    const unsigned short* gBp = Wb + (size_t)2 * 65536;  // peer1
    const unsigned short* gBq = Wb + (size_t)3 * 65536;  // par1
    floatx4 accK[2] = {{0, 0, 0, 0}, {0, 0, 0, 0}};
    floatx4 accC[2] = {{0, 0, 0, 0}, {0, 0, 0, 0}};
#pragma unroll
    for (int kh = 0; kh < 2; ++kh) {
      short8 v[12];
#pragma unroll
      for (int j = 0; j < 12; ++j) {
        int ch = j * 256 + t;
        const unsigned short* src;
        if (j < 4) {
          src = gS2 + (size_t)(r0 + (ch & 63)) * 256 + kh * 128 + (ch >> 6) * 8;
        } else if (j < 5) {
          int cs = ch - 1024;
          src = gS1 + (size_t)(cb0 + (cs & 15)) * 256 + kh * 128 + (cs >> 4) * 8;
        } else if (j < 6) {
          int cs = ch - 1280;
          src = gX0 + (size_t)(cb0 + (cs & 15)) * 256 + kh * 128 + (cs >> 4) * 8;
        } else if (j < 8) {
          int cb = ch - 1536;
          src = gBk + (size_t)(n0 + (cb & 31)) * 256 + kh * 128 + (cb >> 5) * 8;
        } else if (j < 10) {
          int cb = ch - 2048;
          src = gBp + (size_t)(n0 + (cb & 31)) * 256 + kh * 128 + (cb >> 5) * 8;
        } else {
          int cb = ch - 2560;
          src = gBq + (size_t)(n0 + (cb & 31)) * 256 + kh * 128 + (cb >> 5) * 8;
        }
        v[j] = *(const short8*)src;
      }
      __builtin_amdgcn_sched_barrier(0);
#pragma unroll
      for (int j = 0; j < 12; ++j)
        *(short8*)(smem + (size_t)(j * 256 + t) * 16) = v[j];
      __syncthreads();
#pragma unroll
      for (int kk = 0; kk < 4; ++kk) {
        int kq = kk * 4 + q;
        short8 aS = *(const short8*)(smem + (size_t)(kq * 64 + wv * 16 + c) * 16);
        short8 a1 = *(const short8*)(smem + 16384 + (size_t)(kq * 16 + c) * 16);
        short8 ax = *(const short8*)(smem + 20480 + (size_t)(kq * 16 + c) * 16);
#pragma unroll
        for (int nt = 0; nt < 2; ++nt) {
          short8 bk =
              *(const short8*)(smem + 24576 + (size_t)(kq * 32 + nt * 16 + c) * 16);
          short8 bp =
              *(const short8*)(smem + 32768 + (size_t)(kq * 32 + nt * 16 + c) * 16);
          short8 bq =
              *(const short8*)(smem + 40960 + (size_t)(kq * 32 + nt * 16 + c) * 16);
          accK[nt] = MFMA(aS, bk, accK[nt]);
          accC[nt] = MFMA(a1, bp, accC[nt]);
          accC[nt] = MFMA(ax, bq, accC[nt]);
        }
      }
      __syncthreads();
    }
    // epilogue: coarse C tile rows m = coarse row - cb0; out row rg needs
    // m = (wv&1)*8 + 2q + (r>>1); src lane q'' = (wv&1)*2 + (q>>1), reg
    // idx = 2*(q&1) + (r>>1).
    int lsrc = ((wv & 1) * 2 + (q >> 1)) * 16 + c;
#pragma unroll
    for (int nt = 0; nt < 2; ++nt) {
      int n = n0 + nt * 16 + c;
      float s0 = __shfl(accC[nt][0], lsrc);
      float s1 = __shfl(accC[nt][1], lsrc);
      float s2 = __shfl(accC[nt][2], lsrc);
      float s3 = __shfl(accC[nt][3], lsrc);
#pragma unroll
      for (int r = 0; r < 4; ++r) {
        float cv;
        if ((r >> 1) == 0)
          cv = (q & 1) ? s2 : s0;
        else
          cv = (q & 1) ? s3 : s1;
        int rg = r0 + wv * 16 + 4 * q + r;
        out1[(size_t)rg * FD + n] = accK[nt][r] + cv;
      }
    }
  } else {  // ---- out0 ----
    int bid = blockIdx.x - 2048;
    int r0 = (bid >> 3) * 64;
    int n0 = (bid & 7) * 32;
    int cr0 = r0 >> 4;
    const unsigned short* gS1 = ws + OFF_S1;
    const unsigned short* gS0 = ws;  // S0b (144-row padded)
    const unsigned short* gBk = Wb + (size_t)1 * 65536;  // kid0
    const unsigned short* gBp = Wb + (size_t)0 * 65536;  // peer0
    floatx4 accK[2] = {{0, 0, 0, 0}, {0, 0, 0, 0}};
    floatx4 accC[2] = {{0, 0, 0, 0}, {0, 0, 0, 0}};
#pragma unroll
    for (int kh = 0; kh < 2; ++kh) {
      short8 v[9];
#pragma unroll
      for (int j = 0; j < 9; ++j) {
        int ch = j * 256 + t;
        const unsigned short* src;
        if (j < 4) {
          src = gS1 + (size_t)(r0 + (ch & 63)) * 256 + kh * 128 + (ch >> 6) * 8;
        } else if (j < 5) {
          int cs = ch - 1024;
          src = gS0 + (size_t)(cr0 + (cs & 15)) * 256 + kh * 128 + (cs >> 4) * 8;
        } else if (j < 7) {
          int cb = ch - 1280;
          src = gBk + (size_t)(n0 + (cb & 31)) * 256 + kh * 128 + (cb >> 5) * 8;
        } else {
          int cb = ch - 1792;
          src = gBp + (size_t)(n0 + (cb & 31)) * 256 + kh * 128 + (cb >> 5) * 8;
        }
        v[j] = *(const short8*)src;
      }
      __builtin_amdgcn_sched_barrier(0);
#pragma unroll
      for (int j = 0; j < 9; ++j)
        *(short8*)(smem + (size_t)(j * 256 + t) * 16) = v[j];
      __syncthreads();
#pragma unroll
      for (int kk = 0; kk < 4; ++kk) {
        int kq = kk * 4 + q;
        short8 aS = *(const short8*)(smem + (size_t)(kq * 64 + wv * 16 + c) * 16);
        short8 a0 = *(const short8*)(smem + 16384 + (size_t)(kq * 16 + c) * 16);
#pragma unroll
        for (int nt = 0; nt < 2; ++nt) {
          short8 bk =
              *(const short8*)(smem + 20480 + (size_t)(kq * 32 + nt * 16 + c) * 16);
          short8 bp =
              *(const short8*)(smem + 28672 + (size_t)(kq * 32 + nt * 16 + c) * 16);
          accK[nt] = MFMA(aS, bk, accK[nt]);
          accC[nt] = MFMA(a0, bp, accC[nt]);
        }
      }
      __syncthreads();
    }
    // up4: out row (w = 4q+r) needs coarse C row q, col c -> lane c, reg q
#pragma unroll
    for (int nt = 0; nt < 2; ++nt) {
      int n = n0 + nt * 16 + c;
      float s0 = __shfl(accC[nt][0], c);
      float s1 = __shfl(accC[nt][1], c);
      float s2 = __shfl(accC[nt][2], c);
      float s3 = __shfl(accC[nt][3], c);
      float cv = q == 0 ? s0 : q == 1 ? s1 : q == 2 ? s2 : s3;
#pragma unroll
      for (int r = 0; r < 4; ++r)
        out0[(size_t)(r0 + wv * 16 + 4 * q + r) * FD + n] = accK[nt][r] + cv;
    }
  }
}

extern "C" void kernel_launch(void* const* d_in, const int* in_sizes, int n_in,
                              void* d_out, int out_size, void* d_ws,
                              size_t ws_size, hipStream_t stream) {
  const float* x0 = (const float*)d_in[0];  // [8,16,16,256]
  const float* x1 = (const float*)d_in[1];  // [8,32,32,256]
  const float* x2 = (const float*)d_in[2];  // [8,64,64,256]

  const float *kvpeer0, *kvpeer1, *kvpeer2, *kvpar1, *kvpar2, *kvkid0, *kvkid1;
  if (n_in > 4 && in_sizes[4] == 2 * FD * FD) {  // setup_inputs dict order
    kvpeer0 = (const float*)d_in[4];
    kvpeer1 = (const float*)d_in[6];
    kvpeer2 = (const float*)d_in[8];
    kvpar1 = (const float*)d_in[10];
    kvpar2 = (const float*)d_in[12];
    kvkid0 = (const float*)d_in[14];
    kvkid1 = (const float*)d_in[16];
  } else {  // reference() signature order
    kvpeer0 = (const float*)d_in[6];
    kvpeer1 = (const float*)d_in[7];
    kvpeer2 = (const float*)d_in[8];
    kvpar1 = (const float*)d_in[11];
    kvpar2 = (const float*)d_in[12];
    kvkid0 = (const float*)d_in[15];
    kvkid1 = (const float*)d_in[16];
  }

  unsigned short* ws = (unsigned short*)d_ws;  // ~11.5 MB bf16 scratch
  float* out0 = (float*)d_out;
  float* out1 = out0 + (size_t)8 * 16 * 16 * FD;
  float* out2 = out1 + (size_t)8 * 32 * 32 * FD;

  prep<<<3040, 256, 0, stream>>>((const float4*)x0, (const float4*)x1,
                                 (const float4*)x2, kvpeer0, kvkid0, kvpeer1,
                                 kvpar1, kvkid1, kvpeer2, kvpar2, ws);
  gemm<<<2304, 256, 0, stream>>>(ws, out0, out1, out2);
}